// Round 1
// baseline (976.873 us; speedup 1.0000x reference)
//
#include <hip/hip_runtime.h>
#include <hip/hip_bf16.h>

// Problem constants (from reference)
#define NTOK 8192      // B*T = 4*2048
#define DIM 1024
#define NEXP 8
#define HID 2816
#define NPAIR (NTOK * 2)   // TOP_K = 2

// GEMM tiling
#define BM 64
#define BN 64
#define BK 64
#define LDSP 72   // padded LDS row stride (+16B) -> 2-way bank alias only (free)

typedef unsigned short u16;
typedef __attribute__((ext_vector_type(8))) short short8;   // 8 x bf16 fragment
typedef __attribute__((ext_vector_type(4))) float f32x4;    // MFMA accumulator

static __device__ __forceinline__ u16 f2bf(float f) {
  union { float f; unsigned u; } v; v.f = f;
  unsigned r = v.u + 0x7fff + ((v.u >> 16) & 1);  // RTNE
  return (u16)(r >> 16);
}

// ---------------- fp32 -> bf16 conversion (vectorized, grid-stride) ----------
__global__ void cvt_kernel(const float* __restrict__ src, u16* __restrict__ dst, int n) {
  int stride = gridDim.x * blockDim.x;
  for (int i = blockIdx.x * blockDim.x + threadIdx.x; i * 4 < n; i += stride) {
    float4 v = *reinterpret_cast<const float4*>(src + (size_t)i * 4);
    ushort4 o;
    o.x = f2bf(v.x); o.y = f2bf(v.y); o.z = f2bf(v.z); o.w = f2bf(v.w);
    *reinterpret_cast<ushort4*>(dst + (size_t)i * 4) = o;
  }
}

// ---------------- router: logits -> softmax -> top2 -> renorm ----------------
__global__ void router_kernel(const float* __restrict__ x, const float* __restrict__ gw,
                              int* __restrict__ cnt, int* __restrict__ tok_e,
                              float* __restrict__ tok_w) {
  int t = blockIdx.x;
  int lane = threadIdx.x;  // 64 threads = 1 wave
  const float* xr = x + (size_t)t * DIM;
  float acc[NEXP];
#pragma unroll
  for (int e = 0; e < NEXP; ++e) acc[e] = 0.f;
  for (int d = lane; d < DIM; d += 64) {
    float xv = xr[d];
#pragma unroll
    for (int e = 0; e < NEXP; ++e) acc[e] += xv * gw[e * DIM + d];
  }
#pragma unroll
  for (int e = 0; e < NEXP; ++e) {
#pragma unroll
    for (int o = 32; o > 0; o >>= 1) acc[e] += __shfl_xor(acc[e], o);
  }
  if (lane == 0) {
    float m = acc[0];
#pragma unroll
    for (int e = 1; e < NEXP; ++e) m = fmaxf(m, acc[e]);
    float p[NEXP];
#pragma unroll
    for (int e = 0; e < NEXP; ++e) p[e] = __expf(acc[e] - m);
    // top-2 with lowest-index tie-break (matches jax.lax.top_k)
    int e0 = 0; float b0 = p[0];
#pragma unroll
    for (int e = 1; e < NEXP; ++e) if (p[e] > b0) { e0 = e; b0 = p[e]; }
    int e1 = -1; float b1 = -1.f;
#pragma unroll
    for (int e = 0; e < NEXP; ++e) if (e != e0 && p[e] > b1) { e1 = e; b1 = p[e]; }
    float inv = 1.f / (b0 + b1);   // softmax denom cancels in the renorm ratio
    atomicAdd(&cnt[e0], 1);
    atomicAdd(&cnt[e1], 1);
    tok_e[2 * t] = e0; tok_e[2 * t + 1] = e1;
    tok_w[2 * t] = b0 * inv; tok_w[2 * t + 1] = b1 * inv;
  }
}

// ---------------- tiny prefix over 8 experts -------------------------------
__global__ void prefix_kernel(const int* __restrict__ cnt, int* __restrict__ off,
                              int* __restrict__ fill) {
  if (threadIdx.x == 0 && blockIdx.x == 0) {
    int s = 0;
    for (int e = 0; e < NEXP; ++e) { off[e] = s; s += cnt[e]; fill[e] = 0; }
    off[NEXP] = s;   // == NPAIR
  }
}

// ---------------- scatter tokens into per-expert slot lists ----------------
__global__ void scatter_kernel(const int* __restrict__ tok_e, const float* __restrict__ tok_w,
                               const int* __restrict__ off, int* __restrict__ fill,
                               int* __restrict__ pair_tok, float* __restrict__ pair_w) {
  int t = blockIdx.x * blockDim.x + threadIdx.x;
  if (t >= NTOK) return;
#pragma unroll
  for (int k = 0; k < 2; ++k) {
    int e = tok_e[2 * t + k];
    int slot = off[e] + atomicAdd(&fill[e], 1);
    pair_tok[slot] = t;
    pair_w[slot] = tok_w[2 * t + k];
  }
}

// ---------------- GEMM1: h = silu(x @ w1^T) * (x @ w3^T) -------------------
// grid: (tiles_m=NPAIR/BM, HID/BN, NEXP); block 256 = 4 waves (2x2 of 32x32)
__launch_bounds__(256)
__global__ void gemm1_kernel(const u16* __restrict__ xb, const u16* __restrict__ w1b,
                             const u16* __restrict__ w3b, u16* __restrict__ hbuf,
                             const int* __restrict__ off, const int* __restrict__ pair_tok) {
  int e = blockIdx.z;
  int mbase = off[e] + blockIdx.x * BM;
  int mend = off[e + 1];
  if (mbase >= mend) return;              // early-exit empty tiles
  int nrows = mend - mbase; if (nrows > BM) nrows = BM;
  int n0 = blockIdx.y * BN;

  __shared__ u16 As[BM][LDSP];
  __shared__ u16 B1s[BN][LDSP];
  __shared__ u16 B3s[BN][LDSP];

  int tid = threadIdx.x;
  int lane = tid & 63;
  int wid = tid >> 6;
  int wr = wid >> 1, wc = wid & 1;
  int lrow = lane & 15, kgrp = lane >> 4;

  // staging: thread -> (row = tid/4, 16 cols starting at (tid%4)*16)
  int sr = tid >> 2;
  int sc = (tid & 3) << 4;
  int tokA = (sr < nrows) ? pair_tok[mbase + sr] : -1;
  const u16* xA = (tokA >= 0) ? xb + (size_t)tokA * DIM + sc : nullptr;
  const u16* w1p = w1b + (size_t)e * HID * DIM + (size_t)(n0 + sr) * DIM + sc;
  const u16* w3p = w3b + (size_t)e * HID * DIM + (size_t)(n0 + sr) * DIM + sc;

  f32x4 acc1[2][2], acc3[2][2];
#pragma unroll
  for (int i = 0; i < 2; ++i)
#pragma unroll
    for (int j = 0; j < 2; ++j) { acc1[i][j] = (f32x4)0.f; acc3[i][j] = (f32x4)0.f; }

  for (int kk = 0; kk < DIM; kk += BK) {
    uint4 av0, av1;
    if (xA) { av0 = *(const uint4*)(xA + kk); av1 = *(const uint4*)(xA + kk + 8); }
    else { av0 = make_uint4(0, 0, 0, 0); av1 = av0; }
    uint4 b1v0 = *(const uint4*)(w1p + kk), b1v1 = *(const uint4*)(w1p + kk + 8);
    uint4 b3v0 = *(const uint4*)(w3p + kk), b3v1 = *(const uint4*)(w3p + kk + 8);
    __syncthreads();
    *(uint4*)&As[sr][sc] = av0;  *(uint4*)&As[sr][sc + 8] = av1;
    *(uint4*)&B1s[sr][sc] = b1v0; *(uint4*)&B1s[sr][sc + 8] = b1v1;
    *(uint4*)&B3s[sr][sc] = b3v0; *(uint4*)&B3s[sr][sc + 8] = b3v1;
    __syncthreads();
#pragma unroll
    for (int ks = 0; ks < 2; ++ks) {
      int kc = ks * 32 + kgrp * 8;
      short8 a0 = *(const short8*)&As[wr * 32 + lrow][kc];
      short8 a1 = *(const short8*)&As[wr * 32 + 16 + lrow][kc];
      short8 p0 = *(const short8*)&B1s[wc * 32 + lrow][kc];
      short8 p1 = *(const short8*)&B1s[wc * 32 + 16 + lrow][kc];
      short8 q0 = *(const short8*)&B3s[wc * 32 + lrow][kc];
      short8 q1 = *(const short8*)&B3s[wc * 32 + 16 + lrow][kc];
      acc1[0][0] = __builtin_amdgcn_mfma_f32_16x16x32_bf16(a0, p0, acc1[0][0], 0, 0, 0);
      acc1[0][1] = __builtin_amdgcn_mfma_f32_16x16x32_bf16(a0, p1, acc1[0][1], 0, 0, 0);
      acc1[1][0] = __builtin_amdgcn_mfma_f32_16x16x32_bf16(a1, p0, acc1[1][0], 0, 0, 0);
      acc1[1][1] = __builtin_amdgcn_mfma_f32_16x16x32_bf16(a1, p1, acc1[1][1], 0, 0, 0);
      acc3[0][0] = __builtin_amdgcn_mfma_f32_16x16x32_bf16(a0, q0, acc3[0][0], 0, 0, 0);
      acc3[0][1] = __builtin_amdgcn_mfma_f32_16x16x32_bf16(a0, q1, acc3[0][1], 0, 0, 0);
      acc3[1][0] = __builtin_amdgcn_mfma_f32_16x16x32_bf16(a1, q0, acc3[1][0], 0, 0, 0);
      acc3[1][1] = __builtin_amdgcn_mfma_f32_16x16x32_bf16(a1, q1, acc3[1][1], 0, 0, 0);
    }
  }
  // epilogue: silu(acc1)*acc3 -> bf16 h
#pragma unroll
  for (int fm = 0; fm < 2; ++fm)
#pragma unroll
    for (int fn = 0; fn < 2; ++fn)
#pragma unroll
      for (int r = 0; r < 4; ++r) {
        int rowt = wr * 32 + fm * 16 + kgrp * 4 + r;   // C/D: row=(lane>>4)*4+r, col=lane&15
        if (rowt < nrows) {
          float v1 = acc1[fm][fn][r], v3 = acc3[fm][fn][r];
          float hv = v1 / (1.f + __expf(-v1)) * v3;
          hbuf[(size_t)(mbase + rowt) * HID + (n0 + wc * 32 + fn * 16 + lrow)] = f2bf(hv);
        }
      }
}

// ---------------- GEMM2: out[token] += (h @ w2^T) * pair_w -----------------
// grid: (tiles_m=NPAIR/BM, DIM/BN, NEXP); block 256
__launch_bounds__(256)
__global__ void gemm2_kernel(const u16* __restrict__ hbuf, const u16* __restrict__ w2b,
                             float* __restrict__ out, const int* __restrict__ off,
                             const int* __restrict__ pair_tok, const float* __restrict__ pair_w) {
  int e = blockIdx.z;
  int mbase = off[e] + blockIdx.x * BM;
  int mend = off[e + 1];
  if (mbase >= mend) return;
  int nrows = mend - mbase; if (nrows > BM) nrows = BM;
  int n0 = blockIdx.y * BN;

  __shared__ u16 As[BM][LDSP];
  __shared__ u16 Bs[BN][LDSP];

  int tid = threadIdx.x;
  int lane = tid & 63;
  int wid = tid >> 6;
  int wr = wid >> 1, wc = wid & 1;
  int lrow = lane & 15, kgrp = lane >> 4;

  int sr = tid >> 2;
  int sc = (tid & 3) << 4;
  const u16* hA = (sr < nrows) ? hbuf + (size_t)(mbase + sr) * HID + sc : nullptr;
  const u16* w2p = w2b + (size_t)e * DIM * HID + (size_t)(n0 + sr) * HID + sc;

  f32x4 acc[2][2];
#pragma unroll
  for (int i = 0; i < 2; ++i)
#pragma unroll
    for (int j = 0; j < 2; ++j) acc[i][j] = (f32x4)0.f;

  for (int kk = 0; kk < HID; kk += BK) {
    uint4 av0, av1;
    if (hA) { av0 = *(const uint4*)(hA + kk); av1 = *(const uint4*)(hA + kk + 8); }
    else { av0 = make_uint4(0, 0, 0, 0); av1 = av0; }
    uint4 bv0 = *(const uint4*)(w2p + kk), bv1 = *(const uint4*)(w2p + kk + 8);
    __syncthreads();
    *(uint4*)&As[sr][sc] = av0; *(uint4*)&As[sr][sc + 8] = av1;
    *(uint4*)&Bs[sr][sc] = bv0; *(uint4*)&Bs[sr][sc + 8] = bv1;
    __syncthreads();
#pragma unroll
    for (int ks = 0; ks < 2; ++ks) {
      int kc = ks * 32 + kgrp * 8;
      short8 a0 = *(const short8*)&As[wr * 32 + lrow][kc];
      short8 a1 = *(const short8*)&As[wr * 32 + 16 + lrow][kc];
      short8 b0 = *(const short8*)&Bs[wc * 32 + lrow][kc];
      short8 b1 = *(const short8*)&Bs[wc * 32 + 16 + lrow][kc];
      acc[0][0] = __builtin_amdgcn_mfma_f32_16x16x32_bf16(a0, b0, acc[0][0], 0, 0, 0);
      acc[0][1] = __builtin_amdgcn_mfma_f32_16x16x32_bf16(a0, b1, acc[0][1], 0, 0, 0);
      acc[1][0] = __builtin_amdgcn_mfma_f32_16x16x32_bf16(a1, b0, acc[1][0], 0, 0, 0);
      acc[1][1] = __builtin_amdgcn_mfma_f32_16x16x32_bf16(a1, b1, acc[1][1], 0, 0, 0);
    }
  }
#pragma unroll
  for (int fm = 0; fm < 2; ++fm)
#pragma unroll
    for (int fn = 0; fn < 2; ++fn)
#pragma unroll
      for (int r = 0; r < 4; ++r) {
        int rowt = wr * 32 + fm * 16 + kgrp * 4 + r;
        if (rowt < nrows) {
          int slot = mbase + rowt;
          int tok = pair_tok[slot];
          float w = pair_w[slot];
          atomicAdd(&out[(size_t)tok * DIM + (n0 + wc * 32 + fn * 16 + lrow)],
                    acc[fm][fn][r] * w);
        }
      }
}

extern "C" void kernel_launch(void* const* d_in, const int* in_sizes, int n_in,
                              void* d_out, int out_size, void* d_ws, size_t ws_size,
                              hipStream_t stream) {
  const float* x  = (const float*)d_in[0];
  const float* gw = (const float*)d_in[1];
  const float* w1 = (const float*)d_in[2];
  const float* w3 = (const float*)d_in[3];
  const float* w2 = (const float*)d_in[4];
  float* out = (float*)d_out;

  // workspace layout (~248 MB)
  char* base = (char*)d_ws;
  size_t o = 0;
  auto alloc = [&](size_t bytes) {
    void* r = base + o;
    o = (o + bytes + 255) & ~(size_t)255;
    return r;
  };
  u16* xb      = (u16*)alloc((size_t)NTOK * DIM * 2);
  u16* w1b     = (u16*)alloc((size_t)NEXP * HID * DIM * 2);
  u16* w3b     = (u16*)alloc((size_t)NEXP * HID * DIM * 2);
  u16* w2b     = (u16*)alloc((size_t)NEXP * DIM * HID * 2);
  u16* hbuf    = (u16*)alloc((size_t)NPAIR * HID * 2);
  int* pair_tok = (int*)alloc((size_t)NPAIR * 4);
  float* pair_w = (float*)alloc((size_t)NPAIR * 4);
  int* tok_e    = (int*)alloc((size_t)NTOK * 2 * 4);
  float* tok_w  = (float*)alloc((size_t)NTOK * 2 * 4);
  int* cnt      = (int*)alloc(NEXP * 4);
  int* eoff     = (int*)alloc((NEXP + 1) * 4);
  int* fill     = (int*)alloc(NEXP * 4);

  hipMemsetAsync(d_out, 0, (size_t)out_size * sizeof(float), stream);
  hipMemsetAsync(cnt, 0, NEXP * sizeof(int), stream);

  cvt_kernel<<<2048, 256, 0, stream>>>(x,  xb,  NTOK * DIM);
  cvt_kernel<<<2048, 256, 0, stream>>>(w1, w1b, NEXP * HID * DIM);
  cvt_kernel<<<2048, 256, 0, stream>>>(w3, w3b, NEXP * HID * DIM);
  cvt_kernel<<<2048, 256, 0, stream>>>(w2, w2b, NEXP * DIM * HID);

  router_kernel<<<NTOK, 64, 0, stream>>>(x, gw, cnt, tok_e, tok_w);
  prefix_kernel<<<1, 64, 0, stream>>>(cnt, eoff, fill);
  scatter_kernel<<<NTOK / 256, 256, 0, stream>>>(tok_e, tok_w, eoff, fill, pair_tok, pair_w);

  gemm1_kernel<<<dim3(NPAIR / BM, HID / BN, NEXP), 256, 0, stream>>>(
      xb, w1b, w3b, hbuf, eoff, pair_tok);
  gemm2_kernel<<<dim3(NPAIR / BM, DIM / BN, NEXP), 256, 0, stream>>>(
      hbuf, w2b, out, eoff, pair_tok, pair_w);
}